// Round 12
// baseline (91.845 us; speedup 1.0000x reference)
//
#include <hip/hip_runtime.h>
#include <stdint.h>

// NormalizedLoss: batched chamfer + coverage/quality on point clouds.
// x: [32, 2048, 3] fp32, y: [32, 2048, 3] fp32 -> out: [val, cd, cov, qual] fp32.
//
// R12: consolidation of R11's max-occupancy win into R10's 2-dispatch shape.
// 1024-thr blocks (16 waves), full 2048-q staged once (32KB), q split 16-way
// across waves (64 records each), merged[16][256] in-block qc combine ->
// no merge kernel, no 1MB part traffic. LDS 49KB -> 2 blocks/CU = 32 waves/CU
// = 8 waves/SIMD (max TLP, same as R11). launch_bounds(1024,8) caps VGPR 64
// (body uses ~52). Inner loop = R10/R11's proven pk_fma+min3 engine.
// Fixed floor: 40.6us harness ws-poison fill + ~10us launch overhead.

#define BB 32
#define NP 2048
#define BIGF 1e10f

typedef unsigned int u32;
typedef float f2 __attribute__((ext_vector_type(2)));

// embed 11-bit global q-index in the mantissa: float order ~ (d, idx) lex
#define EMB(d, jg) __uint_as_float((__float_as_uint(d) & 0xFFFFF800u) | (jg))

__device__ __forceinline__ f2 pk_fma(f2 a, f2 b, f2 c) {
  f2 d;
  asm("v_pk_fma_f32 %0, %1, %2, %3" : "=v"(d) : "v"(a), "v"(b), "v"(c));
  return d;
}
__device__ __forceinline__ float min3(float a, float b, float c) {
  float r;
  asm("v_min3_f32 %0, %1, %2, %3" : "=v"(r) : "v"(a), "v"(b), "v"(c));
  return r;
}

__global__ __launch_bounds__(1024, 8) void nn_fused_kernel(
    const float* __restrict__ x, const float* __restrict__ y,
    u32* __restrict__ hitpart, float* __restrict__ sums_part,
    float* __restrict__ cnts_part) {
  int bid = blockIdx.x;  // 512 blocks: side(1)|b(5)|pc(3); block = 256 p x 2048 q
  int side = bid >> 8;
  int b = (bid >> 3) & 31;
  int pc = bid & 7;
  int tid = threadIdx.x;
  int w = __builtin_amdgcn_readfirstlane(tid >> 6);  // 0..15, wave-uniform
  int lane = tid & 63;

  __shared__ float4 qs[2048];      // 32KB; rec r -> qs[2r]=(x0,x1,y0,y1), qs[2r+1]=(z0,z1,n0,n1)
  __shared__ u32 merged[16][256];  // 16KB per-wave embedded (d|idx) partials
  __shared__ float pws[256];       // pn (+BIG if invalid) per local p
  __shared__ u32 hitlds[64];       // block-local hit bitmask over 2048 q
  __shared__ float redc[4], redn[4];

  // ---- stage all 2048 q as 1024 pair-records; 1 record (2 q) per thread ----
  {
    const float* qraw = (side ? x : y) + b * NP * 3 + tid * 6;
    f2 a01 = *(const f2*)(qraw);      // x0,y0
    f2 a23 = *(const f2*)(qraw + 2);  // z0,x1
    f2 a45 = *(const f2*)(qraw + 4);  // y1,z1
    float q0x = a01.x, q0y = a01.y, q0z = a23.x;
    float q1x = a23.y, q1y = a45.x, q1z = a45.y;
    float n0 = q0x * q0x + q0y * q0y + q0z * q0z;
    float n1 = q1x * q1x + q1y * q1y + q1z * q1z;
    if (q0x + q0y + q0z == 0.f) n0 += BIGF;  // invalid rows out of every min
    if (q1x + q1y + q1z == 0.f) n1 += BIGF;
    qs[2 * tid]     = make_float4(q0x, q1x, q0y, q1y);
    qs[2 * tid + 1] = make_float4(q0z, q1z, n0, n1);
  }

  // ---- p prologue: every wave loads the SAME 256 p; -2p dup'd into f2 ----
  const float* praw = (side ? y : x) + (b * NP + pc * 256) * 3;
  f2 pmx[4], pmy[4], pmz[4];
  float best[4];
#pragma unroll
  for (int k = 0; k < 4; ++k) {
    int pl = lane + 64 * k;
    float p0 = praw[3 * pl], p1 = praw[3 * pl + 1], p2 = praw[3 * pl + 2];
    pmx[k] = (f2){-2.f * p0, -2.f * p0};
    pmy[k] = (f2){-2.f * p1, -2.f * p1};
    pmz[k] = (f2){-2.f * p2, -2.f * p2};
    if (w == 0) {
      float pn = p0 * p0 + p1 * p1 + p2 * p2;
      if (p0 + p1 + p2 == 0.f) pn += BIGF;
      pws[pl] = pn;
    }
    best[k] = 3.0e38f;
  }
  if (tid < 64) hitlds[tid] = 0u;
  __syncthreads();

  // ---- inner loop: wave's 64 records (128 q) vs its 4 p-points ----
  const float4* qr = &qs[w * 128];
  u32 je = (u32)(w * 128);  // global q index of this wave's record 0
#pragma unroll 8
  for (int r = 0; r < 64; ++r) {
    float4 A = qr[2 * r];      // wave-uniform ds_read_b128 (broadcast)
    float4 B = qr[2 * r + 1];
    f2 qx2 = (f2){A.x, A.y};
    f2 qy2 = (f2){A.z, A.w};
    f2 qz2 = (f2){B.x, B.y};
    f2 qw2 = (f2){B.z, B.w};
    u32 jg = je + 2 * (u32)r, jg1 = jg + 1;
#pragma unroll
    for (int k = 0; k < 4; ++k) {
      f2 d2 = pk_fma(qx2, pmx[k], pk_fma(qy2, pmy[k], pk_fma(qz2, pmz[k], qw2)));
      best[k] = min3(best[k], EMB(d2.x, jg), EMB(d2.y, jg1));
    }
  }

  merged[w][lane +   0] = __float_as_uint(best[0]);
  merged[w][lane +  64] = __float_as_uint(best[1]);
  merged[w][lane + 128] = __float_as_uint(best[2]);
  merged[w][lane + 192] = __float_as_uint(best[3]);
  __syncthreads();

  // ---- merge 16 wave partials; extract (dmin, idx); block-local outputs ----
  float contrib = 0.f, cnt = 0.f;
  if (tid < 256) {
    float bd = __uint_as_float(merged[0][tid]);
#pragma unroll
    for (int ww = 1; ww < 16; ++ww) bd = fminf(bd, __uint_as_float(merged[ww][tid]));
    u32 bits = __float_as_uint(bd);
    u32 bi = bits & 0x7FFu;                            // global q index
    float dmin = __uint_as_float(bits & 0xFFFFF800u);  // truncated min d'
    float pwv = pws[tid];                              // pn (+BIG if invalid p)
    bool valid = (pwv < 1e9f);
    contrib = valid ? (dmin + pwv) : 0.f;              // + ||p||^2, mask invalid
    cnt = valid ? 1.f : 0.f;
    if (valid) atomicOr(&hitlds[bi >> 5], 1u << (bi & 31));
  }
  for (int o = 32; o > 0; o >>= 1) {
    contrib += __shfl_down(contrib, o, 64);
    cnt += __shfl_down(cnt, o, 64);
  }
  if (tid < 256 && lane == 0) { redc[tid >> 6] = contrib; redn[tid >> 6] = cnt; }
  __syncthreads();
  if (tid == 0) {
    sums_part[bid] = redc[0] + redc[1] + redc[2] + redc[3];
    cnts_part[bid] = redn[0] + redn[1] + redn[2] + redn[3];
  }
  if (tid < 64) hitpart[bid * 64 + tid] = hitlds[tid];
}

// One block, 512 threads: 8 threads per (side,b); OR 8 pc-partials, popcount,
// sum part sums/cnts, then one wave assembles the 4 scalars.
__global__ __launch_bounds__(512) void assemble_kernel(const u32* __restrict__ hitpart,
                                                       const float* __restrict__ sums_part,
                                                       const float* __restrict__ cnts_part,
                                                       float* __restrict__ out) {
  __shared__ float hs[64], ss[64], cs[64];
  int tid = threadIdx.x;
  int sb = tid >> 3, c = tid & 7;  // sb = side*32+b; part bid = sb*8 + pc
  float h = 0.f;
  for (int wd = c; wd < 64; wd += 8) {
    u32 m = 0u;
#pragma unroll
    for (int blk = 0; blk < 8; ++blk) m |= hitpart[(sb * 8 + blk) * 64 + wd];
    h += (float)__popc(m);
  }
  h += __shfl_down(h, 4, 8);
  h += __shfl_down(h, 2, 8);
  h += __shfl_down(h, 1, 8);
  if (c == 0) {
    float s = 0.f, n = 0.f;
#pragma unroll
    for (int blk = 0; blk < 8; ++blk) {
      s += sums_part[sb * 8 + blk];
      n += cnts_part[sb * 8 + blk];
    }
    hs[sb] = h; ss[sb] = s; cs[sb] = n;
  }
  __syncthreads();
  if (tid < 64) {
    float cd = 0.f, cov = 0.f, qual = 0.f;
    if (tid < BB) {
      float nx = cs[tid], ny = cs[BB + tid];
      cd = ss[tid] / nx + ss[BB + tid] / ny;
      cov = hs[tid] / ny;        // side0 (p=x) hits y indices: /ny
      qual = hs[BB + tid] / nx;  // side1 (p=y) hits x indices: /nx
    }
    for (int o = 32; o > 0; o >>= 1) {
      cd += __shfl_down(cd, o, 64);
      cov += __shfl_down(cov, o, 64);
      qual += __shfl_down(qual, o, 64);
    }
    if (tid == 0) {
      cd /= (float)BB; cov /= (float)BB; qual /= (float)BB;
      out[0] = cd - 1e-4f * cov - 1e-4f * qual;  // WCD*cd - WCOV*cov - WQUAL*qual
      out[1] = cd;
      out[2] = cov;
      out[3] = qual;
    }
  }
}

extern "C" void kernel_launch(void* const* d_in, const int* in_sizes, int n_in,
                              void* d_out, int out_size, void* d_ws, size_t ws_size,
                              hipStream_t stream) {
  const float* x = (const float*)d_in[0];
  const float* y = (const float*)d_in[1];
  float* out = (float*)d_out;
  char* ws = (char*)d_ws;

  // ws layout (all regions fully written by producers; no memset needed):
  //   [0, 128KB)      hitpart: 512 blocks x 64 u32
  //   [128KB, +2KB)   sums_part: 512 f32
  //   [130KB, +2KB)   cnts_part: 512 f32
  u32* hitpart = (u32*)ws;
  float* sums_part = (float*)(ws + 131072);
  float* cnts_part = (float*)(ws + 133120);

  nn_fused_kernel<<<512, 1024, 0, stream>>>(x, y, hitpart, sums_part, cnts_part);
  assemble_kernel<<<1, 512, 0, stream>>>(hitpart, sums_part, cnts_part, out);
}